// Round 4
// baseline (770.591 us; speedup 1.0000x reference)
//
#include <hip/hip_runtime.h>
#include <hip/hip_bf16.h>

// PatchGINEncoder on MI355X.
// R1: int inputs arrive as int32 (ei[e]=src, ei[E+e]=dst; batch int32[N]).
// R2: sorted-batch bounds; fused MLP; wide aggregate.
// R3: (a) dst-range-SLICED count/scatter (slice = blockIdx&7 -> XCD-local
//         800KB col window; kills the 106MB random partial-line write-back);
//     (b) PANELED feature layout hP[p][n][16] (8 panels x 3.2MB): aggregate
//         block handles one panel; panel fits one XCD's 4MB L2 -> gathers are
//         L2-hits instead of L3. One node per lane, no cross-lane reduction.

#define GDEPTH 3

typedef __bf16 bf16x8 __attribute__((ext_vector_type(8)));
typedef float  f32x4  __attribute__((ext_vector_type(4)));
typedef __hip_bfloat16  bf16;
typedef __hip_bfloat162 bf162;

// ---------------- weight prep: pack W into B-fragment order, fold BN ----------------
// Bp[((kk*4+quad)*128 + n)*8 + j] = W[kk*32+quad*8+j][n]
__global__ void k_prep(const float* __restrict__ W1s, const float* __restrict__ W2s,
                       const float* __restrict__ b1s, const float* __restrict__ bng,
                       const float* __restrict__ bnb, const float* __restrict__ bnm,
                       const float* __restrict__ bnv,
                       bf16* __restrict__ Wp1, bf16* __restrict__ Wp2,
                       float* __restrict__ sArr, float* __restrict__ tArr) {
    int idx = blockIdx.x * 256 + threadIdx.x;      // [0, 6*16384)
    int l   = idx / 32768;
    int rem = idx - l * 32768;
    int w   = rem >> 14;
    int p   = rem & 16383;
    int j = p & 7, n = (p >> 3) & 127, tq = p >> 10;
    int quad = tq & 3, kk = tq >> 2;
    int k = kk * 32 + quad * 8 + j;
    const float* W = w ? W2s : W1s;
    bf16* Wp = w ? Wp2 : Wp1;
    Wp[l * 16384 + p] = __float2bfloat16(W[l * 16384 + k * 128 + n]);
    if (idx < GDEPTH * 128) {
        int ll = idx >> 7, c = idx & 127;
        float inv = rsqrtf(bnv[ll * 128 + c] + 1e-5f);
        float s = inv * bng[ll * 128 + c];
        sArr[idx] = s;
        tArr[idx] = (b1s[ll * 128 + c] - bnm[ll * 128 + c]) * s + bnb[ll * 128 + c];
    }
}

// x (row-major fp32) -> paneled bf16: hP[(c>>1)*N*16 + n*16 + (c&1)*8 ..]
__global__ void k_convert_x(const float4* __restrict__ x4, bf16* __restrict__ hP, int N) {
    int i = blockIdx.x * 256 + threadIdx.x;        // [0, N*16)
    if (i >= N * 16) return;
    int n = i >> 4, c = i & 15;
    float4 a = x4[n * 32 + c * 2];
    float4 b = x4[n * 32 + c * 2 + 1];
    bf16x8 r;
    __hip_bfloat16 t;
    t = __float2bfloat16(a.x); r[0] = *(__bf16*)&t;
    t = __float2bfloat16(a.y); r[1] = *(__bf16*)&t;
    t = __float2bfloat16(a.z); r[2] = *(__bf16*)&t;
    t = __float2bfloat16(a.w); r[3] = *(__bf16*)&t;
    t = __float2bfloat16(b.x); r[4] = *(__bf16*)&t;
    t = __float2bfloat16(b.y); r[5] = *(__bf16*)&t;
    t = __float2bfloat16(b.z); r[6] = *(__bf16*)&t;
    t = __float2bfloat16(b.w); r[7] = *(__bf16*)&t;
    *(bf16x8*)(hP + (size_t)(c >> 1) * N * 16 + (size_t)n * 16 + (c & 1) * 8) = r;
}

// ---------------- sliced CSR build ----------------
// slice = blockIdx&7 covers dst in [s*N/8,(s+1)*N/8); per-XCD-local counters.
#define CSR_CH 4096
__global__ void k_count(const int* __restrict__ ei, int* __restrict__ cnt, int E, int N) {
    int s = blockIdx.x & 7;
    int chunk = blockIdx.x >> 3;
    int lo = (int)((long long)s * N / 8);
    int hi = (int)((long long)(s + 1) * N / 8);
    int base = chunk * CSR_CH;
    #pragma unroll 4
    for (int i = 0; i < CSR_CH / 256; ++i) {
        int e = base + i * 256 + threadIdx.x;
        if (e < E) {
            int d = ei[E + e];
            if (d >= lo && d < hi) atomicAdd(&cnt[d], 1);
        }
    }
}

__global__ void k_scatter(const int* __restrict__ ei, int* __restrict__ fill,
                          int* __restrict__ col, int E, int N) {
    int s = blockIdx.x & 7;
    int chunk = blockIdx.x >> 3;
    int lo = (int)((long long)s * N / 8);
    int hi = (int)((long long)(s + 1) * N / 8);
    int base = chunk * CSR_CH;
    #pragma unroll 4
    for (int i = 0; i < CSR_CH / 256; ++i) {
        int e = base + i * 256 + threadIdx.x;
        if (e < E) {
            int d = ei[E + e];
            if (d >= lo && d < hi) {
                int src = ei[e];
                int pos = atomicAdd(&fill[d], 1);
                col[pos] = src;
            }
        }
    }
}

__global__ void k_scan_blocks(const int* __restrict__ cnt, int* __restrict__ rowp,
                              int* __restrict__ bsums, int n) {
    __shared__ int s[256];
    int t = threadIdx.x;
    int i = blockIdx.x * 256 + t;
    int v = (i < n) ? cnt[i] : 0;
    s[t] = v; __syncthreads();
    for (int o = 1; o < 256; o <<= 1) {
        int u = (t >= o) ? s[t - o] : 0;
        __syncthreads();
        s[t] += u;
        __syncthreads();
    }
    if (i < n) rowp[i] = s[t] - v;
    if (t == 255) bsums[blockIdx.x] = s[255];
}

__global__ void k_scan_sums(int* __restrict__ bsums, int nb) {
    __shared__ int s[512];
    int t = threadIdx.x;
    int v = (t < nb) ? bsums[t] : 0;
    s[t] = v; __syncthreads();
    for (int o = 1; o < 512; o <<= 1) {
        int u = (t >= o) ? s[t - o] : 0;
        __syncthreads();
        s[t] += u;
        __syncthreads();
    }
    if (t < nb) bsums[t] = s[t] - v;
}

__global__ void k_add_off(int* __restrict__ rowp, const int* __restrict__ bsums, int n, int E) {
    int i = blockIdx.x * 256 + threadIdx.x;
    if (i < n) rowp[i] += bsums[blockIdx.x];
    if (i == 0) rowp[n] = E;
}

// ---------------- graph bounds from SORTED batch ----------------
__global__ void k_graph_bounds(const int* __restrict__ batch, int* __restrict__ gp,
                               int n, int G) {
    int i = blockIdx.x * 256 + threadIdx.x;
    if (i >= n) return;
    int b = batch[i];
    if (i == 0) {
        for (int g = 0; g <= b; ++g) gp[g] = 0;
    } else {
        int pb = batch[i - 1];
        if (pb != b) for (int g = pb + 1; g <= b; ++g) gp[g] = i;
    }
    if (i == n - 1) {
        for (int g = b + 1; g <= G; ++g) gp[g] = n;
    }
}

// ---------------- paneled aggregation: zP = hP_self + gather-sum ----------------
// panel = blockIdx&7 (XCD round-robin heuristic -> 3.2MB panel L2-resident).
// One node per lane: acc[16] fp32, 2x16B loads per edge, no cross-lane reduce.
__global__ __launch_bounds__(256) void k_aggregate(const bf16* __restrict__ hP,
                                                   const int* __restrict__ rowp,
                                                   const int* __restrict__ col,
                                                   bf16* __restrict__ zP, int N) {
    int p = blockIdx.x & 7;
    int node = (blockIdx.x >> 3) * 256 + threadIdx.x;
    if (node >= N) return;
    const bf16x8* b8 = (const bf16x8*)(hP + (size_t)p * N * 16);
    bf16x8* z8 = (bf16x8*)(zP + (size_t)p * N * 16);
    bf16x8 s0 = b8[(size_t)node * 2];
    bf16x8 s1 = b8[(size_t)node * 2 + 1];
    float acc[16];
    #pragma unroll
    for (int k = 0; k < 8; ++k) { acc[k] = (float)s0[k]; acc[8 + k] = (float)s1[k]; }
    int e = rowp[node], end = rowp[node + 1];
    for (; e + 1 < end; e += 2) {
        int j0 = col[e], j1 = col[e + 1];
        bf16x8 a0 = b8[(size_t)j0 * 2];
        bf16x8 a1 = b8[(size_t)j0 * 2 + 1];
        bf16x8 c0 = b8[(size_t)j1 * 2];
        bf16x8 c1 = b8[(size_t)j1 * 2 + 1];
        #pragma unroll
        for (int k = 0; k < 8; ++k) {
            acc[k]     += (float)a0[k] + (float)c0[k];
            acc[8 + k] += (float)a1[k] + (float)c1[k];
        }
    }
    if (e < end) {
        int j = col[e];
        bf16x8 a0 = b8[(size_t)j * 2];
        bf16x8 a1 = b8[(size_t)j * 2 + 1];
        #pragma unroll
        for (int k = 0; k < 8; ++k) { acc[k] += (float)a0[k]; acc[8 + k] += (float)a1[k]; }
    }
    bf16x8 r0, r1;
    #pragma unroll
    for (int k = 0; k < 8; ++k) {
        __hip_bfloat16 t0 = __float2bfloat16(acc[k]);
        __hip_bfloat16 t1 = __float2bfloat16(acc[8 + k]);
        r0[k] = *(__bf16*)&t0; r1[k] = *(__bf16*)&t1;
    }
    z8[(size_t)node * 2] = r0;
    z8[(size_t)node * 2 + 1] = r1;
}

// ---------------- fused MLP (paneled I/O): relu(BN(z@W1+b1)) @ W2 + b2, relu ----
__global__ __launch_bounds__(256) void k_mlp(const bf16* __restrict__ A,   // paneled
                                             const bf16* __restrict__ Bp1,
                                             const bf16* __restrict__ Bp2,
                                             const float* __restrict__ sv,
                                             const float* __restrict__ tv,
                                             const float* __restrict__ b2,
                                             bf16* __restrict__ Out, int M) { // paneled
    __shared__ __align__(16) bf16 As[64 * 136];   // row-major 128 feats, +8 pad
    const int tid = threadIdx.x;
    const int m0 = blockIdx.x * 64;
    {
        int c = tid & 15;                  // 16B chunk: panel c>>1, half c&1
        int r0 = tid >> 4;
        size_t pbase = (size_t)(c >> 1) * M * 16 + (c & 1) * 8;
        #pragma unroll
        for (int rr = 0; rr < 4; ++rr) {
            int r = r0 + rr * 16;
            int gr = m0 + r;
            uint4 val = make_uint4(0, 0, 0, 0);
            if (gr < M) val = *(const uint4*)(A + pbase + (size_t)gr * 16);
            *(uint4*)(As + r * 136 + c * 8) = val;
        }
    }
    const int lane = tid & 63;
    const int wid = tid >> 6;
    const int wm = wid & 1, wn = wid >> 1;
    const int l15 = lane & 15, quad = lane >> 4;

    bf16x8 b1[4][4];
    #pragma unroll
    for (int kk = 0; kk < 4; ++kk)
        #pragma unroll
        for (int tn = 0; tn < 4; ++tn)
            b1[kk][tn] = *(const bf16x8*)(Bp1 + ((kk * 4 + quad) * 128 + wn * 64 + tn * 16 + l15) * 8);

    __syncthreads();
    f32x4 acc[2][4];
    #pragma unroll
    for (int i = 0; i < 2; ++i)
        #pragma unroll
        for (int j = 0; j < 4; ++j) acc[i][j] = (f32x4){0.f, 0.f, 0.f, 0.f};
    #pragma unroll
    for (int kk = 0; kk < 4; ++kk) {
        bf16x8 a[2];
        #pragma unroll
        for (int tm = 0; tm < 2; ++tm)
            a[tm] = *(const bf16x8*)(As + (wm * 32 + tm * 16 + l15) * 136 + kk * 32 + quad * 8);
        #pragma unroll
        for (int tm = 0; tm < 2; ++tm)
            #pragma unroll
            for (int tn = 0; tn < 4; ++tn)
                acc[tm][tn] = __builtin_amdgcn_mfma_f32_16x16x32_bf16(a[tm], b1[kk][tn], acc[tm][tn], 0, 0, 0);
    }
    __syncthreads();
    #pragma unroll
    for (int tn = 0; tn < 4; ++tn) {
        int gc = wn * 64 + tn * 16 + l15;
        float scale = sv[gc], shift = tv[gc];
        #pragma unroll
        for (int tm = 0; tm < 2; ++tm)
            #pragma unroll
            for (int r = 0; r < 4; ++r) {
                float v = fmaxf(acc[tm][tn][r] * scale + shift, 0.f);
                int row = wm * 32 + tm * 16 + quad * 4 + r;
                __hip_bfloat16 t = __float2bfloat16(v);
                As[row * 136 + gc] = *(bf16*)&t;
            }
    }
    bf16x8 b2f[4][4];
    #pragma unroll
    for (int kk = 0; kk < 4; ++kk)
        #pragma unroll
        for (int tn = 0; tn < 4; ++tn)
            b2f[kk][tn] = *(const bf16x8*)(Bp2 + ((kk * 4 + quad) * 128 + wn * 64 + tn * 16 + l15) * 8);
    __syncthreads();
    #pragma unroll
    for (int i = 0; i < 2; ++i)
        #pragma unroll
        for (int j = 0; j < 4; ++j) acc[i][j] = (f32x4){0.f, 0.f, 0.f, 0.f};
    #pragma unroll
    for (int kk = 0; kk < 4; ++kk) {
        bf16x8 a[2];
        #pragma unroll
        for (int tm = 0; tm < 2; ++tm)
            a[tm] = *(const bf16x8*)(As + (wm * 32 + tm * 16 + l15) * 136 + kk * 32 + quad * 8);
        #pragma unroll
        for (int tm = 0; tm < 2; ++tm)
            #pragma unroll
            for (int tn = 0; tn < 4; ++tn)
                acc[tm][tn] = __builtin_amdgcn_mfma_f32_16x16x32_bf16(a[tm], b2f[kk][tn], acc[tm][tn], 0, 0, 0);
    }
    // epilogue2 -> paneled Out: (gr,gc) -> panel gc>>4, offset gr*16 + (gc&15)
    #pragma unroll
    for (int tn = 0; tn < 4; ++tn) {
        int gc = wn * 64 + tn * 16 + l15;
        float shift = b2[gc];
        size_t pbase = (size_t)(gc >> 4) * M * 16 + (gc & 15);
        #pragma unroll
        for (int tm = 0; tm < 2; ++tm)
            #pragma unroll
            for (int r = 0; r < 4; ++r) {
                int gr = m0 + wm * 32 + tm * 16 + quad * 4 + r;
                if (gr < M) {
                    float v = fmaxf(acc[tm][tn][r] + shift, 0.f);
                    Out[pbase + (size_t)gr * 16] = __float2bfloat16(v);
                }
            }
    }
}

// ---------------- pooling (paneled input, sorted batch) ----------------
__global__ void k_pool(const bf16* __restrict__ hP, const int* __restrict__ gp,
                       float* __restrict__ hg, int N) {
    int g = blockIdx.x, t = threadIdx.x;       // 128 threads; feature t
    int s = gp[g], e = gp[g + 1];
    size_t pbase = (size_t)(t >> 4) * N * 16 + (t & 15);
    float acc = 0.f;
    for (int i = s; i < e; ++i) acc += __bfloat162float(*(const bf16*)(hP + pbase + (size_t)i * 16));
    int c = e - s; if (c < 1) c = 1;
    hg[g * 128 + t] = acc / (float)c;
}

// ---------------- projection + LayerNorm (fp32) ----------------
__global__ void k_proj_ln(const float* __restrict__ hg, const float* __restrict__ Wp,
                          const float* __restrict__ bp, const float* __restrict__ lng,
                          const float* __restrict__ lnb, float* __restrict__ out) {
    __shared__ float row[128];
    __shared__ float red[128];
    int g = blockIdx.x, t = threadIdx.x;
    row[t] = hg[g * 128 + t];
    __syncthreads();
    float p = bp[t];
    #pragma unroll 8
    for (int k = 0; k < 128; ++k) p += row[k] * Wp[k * 128 + t];
    red[t] = p; __syncthreads();
    for (int o = 64; o > 0; o >>= 1) { if (t < o) red[t] += red[t + o]; __syncthreads(); }
    float mu = red[0] * (1.0f / 128.0f);
    __syncthreads();
    float d = p - mu;
    red[t] = d * d; __syncthreads();
    for (int o = 64; o > 0; o >>= 1) { if (t < o) red[t] += red[t + o]; __syncthreads(); }
    float var = red[0] * (1.0f / 128.0f);
    out[g * 128 + t] = d * rsqrtf(var + 1e-5f) * lng[t] + lnb[t];
}

extern "C" void kernel_launch(void* const* d_in, const int* in_sizes, int n_in,
                              void* d_out, int out_size, void* d_ws, size_t ws_size,
                              hipStream_t stream) {
    const float* x   = (const float*)d_in[0];
    const int*   ei  = (const int*)d_in[1];    // int32: [src(E), dst(E)]
    const int*   bat = (const int*)d_in[2];    // int32, sorted
    const float* W1s = (const float*)d_in[3];
    const float* b1s = (const float*)d_in[4];
    const float* bng = (const float*)d_in[5];
    const float* bnb = (const float*)d_in[6];
    const float* bnm = (const float*)d_in[7];
    const float* bnv = (const float*)d_in[8];
    const float* W2s = (const float*)d_in[9];
    const float* b2s = (const float*)d_in[10];
    const float* Wp  = (const float*)d_in[11];
    const float* bp  = (const float*)d_in[12];
    const float* lng = (const float*)d_in[13];
    const float* lnb = (const float*)d_in[14];
    const int E = in_sizes[1] / 2;
    const int N = in_sizes[2];
    const int G = out_size / 128;

    char* w = (char*)d_ws;
    size_t off = 0;
    auto alloc = [&](size_t b) { char* p = w + off; off += (b + 255) & ~(size_t)255; return p; };
    bf16* buf_a = (bf16*)alloc((size_t)N * 128 * 2);
    bf16* buf_b = (bf16*)alloc((size_t)N * 128 * 2);
    int* col   = (int*)alloc((size_t)E * 4);
    int* cnt   = (int*)alloc((size_t)N * 4);
    int* rowp  = (int*)alloc((size_t)(N + 1) * 4);
    int* fill  = (int*)alloc((size_t)N * 4);
    int* bsums = (int*)alloc(4096);
    int* gp    = (int*)alloc(2048);
    bf16* Wp1  = (bf16*)alloc((size_t)GDEPTH * 16384 * 2);
    bf16* Wp2  = (bf16*)alloc((size_t)GDEPTH * 16384 * 2);
    float* sA  = (float*)alloc((size_t)GDEPTH * 128 * 4);
    float* tA  = (float*)alloc((size_t)GDEPTH * 128 * 4);
    float* hg  = (float*)alloc((size_t)G * 128 * 4);

    hipMemsetAsync(cnt, 0, (size_t)N * 4, stream);

    k_prep<<<384, 256, 0, stream>>>(W1s, W2s, b1s, bng, bnb, bnm, bnv, Wp1, Wp2, sA, tA);
    k_convert_x<<<(N * 16 + 255) / 256, 256, 0, stream>>>((const float4*)x, buf_a, N);

    int nb = (N + 255) / 256;
    int csr_blocks = ((E + CSR_CH - 1) / CSR_CH) * 8;
    k_count<<<csr_blocks, 256, 0, stream>>>(ei, cnt, E, N);
    k_graph_bounds<<<nb, 256, 0, stream>>>(bat, gp, N, G);
    k_scan_blocks<<<nb, 256, 0, stream>>>(cnt, rowp, bsums, N);
    k_scan_sums<<<1, 512, 0, stream>>>(bsums, nb);
    k_add_off<<<nb, 256, 0, stream>>>(rowp, bsums, N, E);
    hipMemcpyAsync(fill, rowp, (size_t)N * 4, hipMemcpyDeviceToDevice, stream);
    k_scatter<<<csr_blocks, 256, 0, stream>>>(ei, fill, col, E, N);

    const bf16* hcur = buf_a;
    bf16* hz = buf_b;
    for (int l = 0; l < GDEPTH; ++l) {
        k_aggregate<<<nb * 8, 256, 0, stream>>>(hcur, rowp, col, hz, N);
        k_mlp<<<(N + 63) / 64, 256, 0, stream>>>(hz, Wp1 + (size_t)l * 16384,
                                                 Wp2 + (size_t)l * 16384,
                                                 sA + l * 128, tA + l * 128,
                                                 b2s + l * 128, hz, N);
        bf16* tmp = hz; hz = (bf16*)hcur; hcur = tmp;
    }
    k_pool<<<G, 128, 0, stream>>>(hcur, gp, hg, N);
    k_proj_ln<<<G, 128, 0, stream>>>(hg, Wp, bp, lng, lnb, (float*)d_out);
}

// Round 5
// 647.636 us; speedup vs baseline: 1.1899x; 1.1899x over previous
//
#include <hip/hip_runtime.h>
#include <hip/hip_bf16.h>

// PatchGINEncoder on MI355X.
// R1: int inputs arrive as int32 (ei[e]=src, ei[E+e]=dst; batch int32[N]).
// R2: sorted-batch bounds; fused MLP; wide aggregate.
// R3: dst-range-sliced count/scatter (fixed 106MB random write-back).
// R4 (FAILED): feature paneling -> 2x line over-fetch (FETCH 269MB/dispatch),
//     XCD-affinity bet didn't hold. Reverted.
// R5: row-major layout restored; aggregate FUSED into MLP (k_layer): block
//     gathers its 64 rows directly into MFMA staging LDS (full-row coalesced,
//     unroll-4), then double-GEMM. Kills z round-trip (51MB/layer) + 3 launches;
//     gather waves overlap MFMA waves across blocks. B-frags per-kk from global
//     (L1-hot 32KB) to keep VGPRs low for gather occupancy.

#define GDEPTH 3

typedef __bf16 bf16x8 __attribute__((ext_vector_type(8)));
typedef float  f32x4  __attribute__((ext_vector_type(4)));
typedef __hip_bfloat16  bf16;
typedef __hip_bfloat162 bf162;

// ---------------- weight prep: pack W into B-fragment order, fold BN ----------------
// Bp[((kk*4+quad)*128 + n)*8 + j] = W[kk*32+quad*8+j][n]
__global__ void k_prep(const float* __restrict__ W1s, const float* __restrict__ W2s,
                       const float* __restrict__ b1s, const float* __restrict__ bng,
                       const float* __restrict__ bnb, const float* __restrict__ bnm,
                       const float* __restrict__ bnv,
                       bf16* __restrict__ Wp1, bf16* __restrict__ Wp2,
                       float* __restrict__ sArr, float* __restrict__ tArr) {
    int idx = blockIdx.x * 256 + threadIdx.x;      // [0, 6*16384)
    int l   = idx / 32768;
    int rem = idx - l * 32768;
    int w   = rem >> 14;
    int p   = rem & 16383;
    int j = p & 7, n = (p >> 3) & 127, tq = p >> 10;
    int quad = tq & 3, kk = tq >> 2;
    int k = kk * 32 + quad * 8 + j;
    const float* W = w ? W2s : W1s;
    bf16* Wp = w ? Wp2 : Wp1;
    Wp[l * 16384 + p] = __float2bfloat16(W[l * 16384 + k * 128 + n]);
    if (idx < GDEPTH * 128) {
        int ll = idx >> 7, c = idx & 127;
        float inv = rsqrtf(bnv[ll * 128 + c] + 1e-5f);
        float s = inv * bng[ll * 128 + c];
        sArr[idx] = s;
        tArr[idx] = (b1s[ll * 128 + c] - bnm[ll * 128 + c]) * s + bnb[ll * 128 + c];
    }
}

__global__ void k_convert_x(const float4* __restrict__ x, bf162* __restrict__ h, int n4) {
    int i = blockIdx.x * 256 + threadIdx.x;
    if (i >= n4) return;
    float4 v = x[i];
    bf162 a, b;
    a.x = __float2bfloat16(v.x); a.y = __float2bfloat16(v.y);
    b.x = __float2bfloat16(v.z); b.y = __float2bfloat16(v.w);
    h[2 * i] = a; h[2 * i + 1] = b;
}

// ---------------- sliced CSR build ----------------
#define CSR_CH 4096
__global__ void k_count(const int* __restrict__ ei, int* __restrict__ cnt, int E, int N) {
    int s = blockIdx.x & 7;
    int chunk = blockIdx.x >> 3;
    int lo = (int)((long long)s * N / 8);
    int hi = (int)((long long)(s + 1) * N / 8);
    int base = chunk * CSR_CH;
    #pragma unroll 4
    for (int i = 0; i < CSR_CH / 256; ++i) {
        int e = base + i * 256 + threadIdx.x;
        if (e < E) {
            int d = ei[E + e];
            if (d >= lo && d < hi) atomicAdd(&cnt[d], 1);
        }
    }
}

__global__ void k_scatter(const int* __restrict__ ei, int* __restrict__ fill,
                          int* __restrict__ col, int E, int N) {
    int s = blockIdx.x & 7;
    int chunk = blockIdx.x >> 3;
    int lo = (int)((long long)s * N / 8);
    int hi = (int)((long long)(s + 1) * N / 8);
    int base = chunk * CSR_CH;
    #pragma unroll 4
    for (int i = 0; i < CSR_CH / 256; ++i) {
        int e = base + i * 256 + threadIdx.x;
        if (e < E) {
            int d = ei[E + e];
            if (d >= lo && d < hi) {
                int src = ei[e];
                int pos = atomicAdd(&fill[d], 1);
                col[pos] = src;
            }
        }
    }
}

__global__ void k_scan_blocks(const int* __restrict__ cnt, int* __restrict__ rowp,
                              int* __restrict__ bsums, int n) {
    __shared__ int s[256];
    int t = threadIdx.x;
    int i = blockIdx.x * 256 + t;
    int v = (i < n) ? cnt[i] : 0;
    s[t] = v; __syncthreads();
    for (int o = 1; o < 256; o <<= 1) {
        int u = (t >= o) ? s[t - o] : 0;
        __syncthreads();
        s[t] += u;
        __syncthreads();
    }
    if (i < n) rowp[i] = s[t] - v;
    if (t == 255) bsums[blockIdx.x] = s[255];
}

__global__ void k_scan_sums(int* __restrict__ bsums, int nb) {
    __shared__ int s[512];
    int t = threadIdx.x;
    int v = (t < nb) ? bsums[t] : 0;
    s[t] = v; __syncthreads();
    for (int o = 1; o < 512; o <<= 1) {
        int u = (t >= o) ? s[t - o] : 0;
        __syncthreads();
        s[t] += u;
        __syncthreads();
    }
    if (t < nb) bsums[t] = s[t] - v;
}

__global__ void k_add_off(int* __restrict__ rowp, const int* __restrict__ bsums, int n, int E) {
    int i = blockIdx.x * 256 + threadIdx.x;
    if (i < n) rowp[i] += bsums[blockIdx.x];
    if (i == 0) rowp[n] = E;
}

// ---------------- graph bounds from SORTED batch ----------------
__global__ void k_graph_bounds(const int* __restrict__ batch, int* __restrict__ gp,
                               int n, int G) {
    int i = blockIdx.x * 256 + threadIdx.x;
    if (i >= n) return;
    int b = batch[i];
    if (i == 0) {
        for (int g = 0; g <= b; ++g) gp[g] = 0;
    } else {
        int pb = batch[i - 1];
        if (pb != b) for (int g = pb + 1; g <= b; ++g) gp[g] = i;
    }
    if (i == n - 1) {
        for (int g = b + 1; g <= G; ++g) gp[g] = n;
    }
}

// ---------------- fused layer: z = h + Ah (gather) -> relu(BN(zW1+b1))W2+b2, relu --
// Block owns 64 rows. Phase 1: 16 groups x 16 lanes gather full 256B rows
// (fp32 acc, 4 edges in flight) straight into MFMA staging LDS. Phase 2:
// double MFMA GEMM with per-kk B-frag loads (L1-hot). Out != h (ping-pong).
__global__ __launch_bounds__(256) void k_layer(const bf16* __restrict__ h,
                                               const int* __restrict__ rowp,
                                               const int* __restrict__ col,
                                               const bf16* __restrict__ Bp1,
                                               const bf16* __restrict__ Bp2,
                                               const float* __restrict__ sv,
                                               const float* __restrict__ tv,
                                               const float* __restrict__ b2,
                                               bf16* __restrict__ Out, int M) {
    __shared__ __align__(16) bf16 As[64 * 136];   // +8 pad
    const int tid = threadIdx.x;
    const int m0 = blockIdx.x * 64;
    const int grp = tid >> 4, c = tid & 15;
    const bf16x8* h8 = (const bf16x8*)h;           // row j chunk c at h8[j*16+c]

    #pragma unroll
    for (int it = 0; it < 4; ++it) {
        int row = grp * 4 + it;
        int node = m0 + row;
        float acc[8];
        if (node < M) {
            bf16x8 self = h8[(size_t)node * 16 + c];
            #pragma unroll
            for (int k = 0; k < 8; ++k) acc[k] = (float)self[k];
            int e = rowp[node], end = rowp[node + 1];
            for (; e + 3 < end; e += 4) {
                int j0 = col[e], j1 = col[e + 1], j2 = col[e + 2], j3 = col[e + 3];
                bf16x8 v0 = h8[(size_t)j0 * 16 + c];
                bf16x8 v1 = h8[(size_t)j1 * 16 + c];
                bf16x8 v2 = h8[(size_t)j2 * 16 + c];
                bf16x8 v3 = h8[(size_t)j3 * 16 + c];
                #pragma unroll
                for (int k = 0; k < 8; ++k)
                    acc[k] += ((float)v0[k] + (float)v1[k]) + ((float)v2[k] + (float)v3[k]);
            }
            for (; e < end; ++e) {
                bf16x8 v = h8[(size_t)col[e] * 16 + c];
                #pragma unroll
                for (int k = 0; k < 8; ++k) acc[k] += (float)v[k];
            }
        } else {
            #pragma unroll
            for (int k = 0; k < 8; ++k) acc[k] = 0.f;
        }
        bf16x8 r;
        #pragma unroll
        for (int k = 0; k < 8; ++k) {
            __hip_bfloat16 t = __float2bfloat16(acc[k]);
            r[k] = *(__bf16*)&t;
        }
        *(bf16x8*)(As + row * 136 + c * 8) = r;
    }
    __syncthreads();

    const int lane = tid & 63;
    const int wid = tid >> 6;
    const int wm = wid & 1, wn = wid >> 1;
    const int l15 = lane & 15, quad = lane >> 4;

    f32x4 acc[2][4];
    #pragma unroll
    for (int i = 0; i < 2; ++i)
        #pragma unroll
        for (int j = 0; j < 4; ++j) acc[i][j] = (f32x4){0.f, 0.f, 0.f, 0.f};
    #pragma unroll
    for (int kk = 0; kk < 4; ++kk) {
        bf16x8 a[2], b[4];
        #pragma unroll
        for (int tn = 0; tn < 4; ++tn)
            b[tn] = *(const bf16x8*)(Bp1 + ((kk * 4 + quad) * 128 + wn * 64 + tn * 16 + l15) * 8);
        #pragma unroll
        for (int tm = 0; tm < 2; ++tm)
            a[tm] = *(const bf16x8*)(As + (wm * 32 + tm * 16 + l15) * 136 + kk * 32 + quad * 8);
        #pragma unroll
        for (int tm = 0; tm < 2; ++tm)
            #pragma unroll
            for (int tn = 0; tn < 4; ++tn)
                acc[tm][tn] = __builtin_amdgcn_mfma_f32_16x16x32_bf16(a[tm], b[tn], acc[tm][tn], 0, 0, 0);
    }
    __syncthreads();                               // all GEMM1 A-reads done
    // epilogue1: y = relu(acc*s + t) -> LDS (C/D: col=lane&15, row=quad*4+reg)
    #pragma unroll
    for (int tn = 0; tn < 4; ++tn) {
        int gc = wn * 64 + tn * 16 + l15;
        float scale = sv[gc], shift = tv[gc];
        #pragma unroll
        for (int tm = 0; tm < 2; ++tm)
            #pragma unroll
            for (int r = 0; r < 4; ++r) {
                float v = fmaxf(acc[tm][tn][r] * scale + shift, 0.f);
                int row = wm * 32 + tm * 16 + quad * 4 + r;
                __hip_bfloat16 t = __float2bfloat16(v);
                As[row * 136 + gc] = *(bf16*)&t;
            }
    }
    __syncthreads();                               // y fully in LDS
    #pragma unroll
    for (int i = 0; i < 2; ++i)
        #pragma unroll
        for (int j = 0; j < 4; ++j) acc[i][j] = (f32x4){0.f, 0.f, 0.f, 0.f};
    #pragma unroll
    for (int kk = 0; kk < 4; ++kk) {
        bf16x8 a[2], b[4];
        #pragma unroll
        for (int tn = 0; tn < 4; ++tn)
            b[tn] = *(const bf16x8*)(Bp2 + ((kk * 4 + quad) * 128 + wn * 64 + tn * 16 + l15) * 8);
        #pragma unroll
        for (int tm = 0; tm < 2; ++tm)
            a[tm] = *(const bf16x8*)(As + (wm * 32 + tm * 16 + l15) * 136 + kk * 32 + quad * 8);
        #pragma unroll
        for (int tm = 0; tm < 2; ++tm)
            #pragma unroll
            for (int tn = 0; tn < 4; ++tn)
                acc[tm][tn] = __builtin_amdgcn_mfma_f32_16x16x32_bf16(a[tm], b[tn], acc[tm][tn], 0, 0, 0);
    }
    // epilogue2: h_next = relu(acc + b2) -> global (different buffer)
    #pragma unroll
    for (int tn = 0; tn < 4; ++tn) {
        int gc = wn * 64 + tn * 16 + l15;
        float shift = b2[gc];
        #pragma unroll
        for (int tm = 0; tm < 2; ++tm)
            #pragma unroll
            for (int r = 0; r < 4; ++r) {
                int gr = m0 + wm * 32 + tm * 16 + quad * 4 + r;
                if (gr < M) {
                    float v = fmaxf(acc[tm][tn][r] + shift, 0.f);
                    Out[(size_t)gr * 128 + gc] = __float2bfloat16(v);
                }
            }
    }
}

// ---------------- pooling (sorted batch -> contiguous ranges) ----------------
__global__ void k_pool(const bf16* __restrict__ h, const int* __restrict__ gp,
                       float* __restrict__ hg) {
    int g = blockIdx.x, t = threadIdx.x;       // 128 threads
    int s = gp[g], e = gp[g + 1];
    float acc = 0.f;
    for (int i = s; i < e; ++i) acc += __bfloat162float(h[(size_t)i * 128 + t]);
    int c = e - s; if (c < 1) c = 1;
    hg[g * 128 + t] = acc / (float)c;
}

// ---------------- projection + LayerNorm (fp32) ----------------
__global__ void k_proj_ln(const float* __restrict__ hg, const float* __restrict__ Wp,
                          const float* __restrict__ bp, const float* __restrict__ lng,
                          const float* __restrict__ lnb, float* __restrict__ out) {
    __shared__ float row[128];
    __shared__ float red[128];
    int g = blockIdx.x, t = threadIdx.x;
    row[t] = hg[g * 128 + t];
    __syncthreads();
    float p = bp[t];
    #pragma unroll 8
    for (int k = 0; k < 128; ++k) p += row[k] * Wp[k * 128 + t];
    red[t] = p; __syncthreads();
    for (int o = 64; o > 0; o >>= 1) { if (t < o) red[t] += red[t + o]; __syncthreads(); }
    float mu = red[0] * (1.0f / 128.0f);
    __syncthreads();
    float d = p - mu;
    red[t] = d * d; __syncthreads();
    for (int o = 64; o > 0; o >>= 1) { if (t < o) red[t] += red[t + o]; __syncthreads(); }
    float var = red[0] * (1.0f / 128.0f);
    out[g * 128 + t] = d * rsqrtf(var + 1e-5f) * lng[t] + lnb[t];
}

extern "C" void kernel_launch(void* const* d_in, const int* in_sizes, int n_in,
                              void* d_out, int out_size, void* d_ws, size_t ws_size,
                              hipStream_t stream) {
    const float* x   = (const float*)d_in[0];
    const int*   ei  = (const int*)d_in[1];    // int32: [src(E), dst(E)]
    const int*   bat = (const int*)d_in[2];    // int32, sorted
    const float* W1s = (const float*)d_in[3];
    const float* b1s = (const float*)d_in[4];
    const float* bng = (const float*)d_in[5];
    const float* bnb = (const float*)d_in[6];
    const float* bnm = (const float*)d_in[7];
    const float* bnv = (const float*)d_in[8];
    const float* W2s = (const float*)d_in[9];
    const float* b2s = (const float*)d_in[10];
    const float* Wp  = (const float*)d_in[11];
    const float* bp  = (const float*)d_in[12];
    const float* lng = (const float*)d_in[13];
    const float* lnb = (const float*)d_in[14];
    const int E = in_sizes[1] / 2;
    const int N = in_sizes[2];
    const int G = out_size / 128;

    char* w = (char*)d_ws;
    size_t off = 0;
    auto alloc = [&](size_t b) { char* p = w + off; off += (b + 255) & ~(size_t)255; return p; };
    bf16* buf_a = (bf16*)alloc((size_t)N * 128 * 2);
    bf16* buf_b = (bf16*)alloc((size_t)N * 128 * 2);
    int* col   = (int*)alloc((size_t)E * 4);
    int* cnt   = (int*)alloc((size_t)N * 4);
    int* rowp  = (int*)alloc((size_t)(N + 1) * 4);
    int* fill  = (int*)alloc((size_t)N * 4);
    int* bsums = (int*)alloc(4096);
    int* gp    = (int*)alloc(2048);
    bf16* Wp1  = (bf16*)alloc((size_t)GDEPTH * 16384 * 2);
    bf16* Wp2  = (bf16*)alloc((size_t)GDEPTH * 16384 * 2);
    float* sA  = (float*)alloc((size_t)GDEPTH * 128 * 4);
    float* tA  = (float*)alloc((size_t)GDEPTH * 128 * 4);
    float* hg  = (float*)alloc((size_t)G * 128 * 4);

    hipMemsetAsync(cnt, 0, (size_t)N * 4, stream);

    k_prep<<<384, 256, 0, stream>>>(W1s, W2s, b1s, bng, bnb, bnm, bnv, Wp1, Wp2, sA, tA);
    k_convert_x<<<(N * 32 + 255) / 256, 256, 0, stream>>>((const float4*)x, (bf162*)buf_a, N * 32);

    int nb = (N + 255) / 256;
    int csr_blocks = ((E + CSR_CH - 1) / CSR_CH) * 8;
    k_count<<<csr_blocks, 256, 0, stream>>>(ei, cnt, E, N);
    k_graph_bounds<<<nb, 256, 0, stream>>>(bat, gp, N, G);
    k_scan_blocks<<<nb, 256, 0, stream>>>(cnt, rowp, bsums, N);
    k_scan_sums<<<1, 512, 0, stream>>>(bsums, nb);
    k_add_off<<<nb, 256, 0, stream>>>(rowp, bsums, N, E);
    hipMemcpyAsync(fill, rowp, (size_t)N * 4, hipMemcpyDeviceToDevice, stream);
    k_scatter<<<csr_blocks, 256, 0, stream>>>(ei, fill, col, E, N);

    const bf16* hcur = buf_a;
    bf16* hnext = buf_b;
    for (int l = 0; l < GDEPTH; ++l) {
        k_layer<<<(N + 63) / 64, 256, 0, stream>>>(hcur, rowp, col,
                                                   Wp1 + (size_t)l * 16384,
                                                   Wp2 + (size_t)l * 16384,
                                                   sA + l * 128, tA + l * 128,
                                                   b2s + l * 128, hnext, N);
        bf16* tmp = hnext; hnext = (bf16*)hcur; hcur = tmp;
    }
    k_pool<<<G, 128, 0, stream>>>(hcur, gp, hg);
    k_proj_ln<<<G, 128, 0, stream>>>(hg, Wp, bp, lng, lnb, (float*)d_out);
}

// Round 6
// 583.689 us; speedup vs baseline: 1.3202x; 1.1096x over previous
//
#include <hip/hip_runtime.h>
#include <hip/hip_bf16.h>

// PatchGINEncoder on MI355X.
// R1: int inputs arrive as int32 (ei[e]=src, ei[E+e]=dst; batch int32[N]).
// R2: sorted-batch bounds; fused MLP; wide aggregate.
// R3: dst-range-sliced count/scatter (fixed 106MB random write-back).
// R4 (FAILED): feature paneling -> 2x line over-fetch. Reverted.
// R5: aggregate fused into MLP (k_layer); gather straight into MFMA LDS.
// R6: k_pool was 105us at 4.8% occupancy (256 blocks, serial 390-row walk).
//     Re-parallelized over node chunks (782 blocks) + fp32 atomic flush at
//     sorted-batch graph boundaries; mean-divide folded into k_proj_ln.

#define GDEPTH 3

typedef __bf16 bf16x8 __attribute__((ext_vector_type(8)));
typedef float  f32x4  __attribute__((ext_vector_type(4)));
typedef __hip_bfloat16  bf16;
typedef __hip_bfloat162 bf162;

// ---------------- weight prep: pack W into B-fragment order, fold BN ----------------
// Bp[((kk*4+quad)*128 + n)*8 + j] = W[kk*32+quad*8+j][n]
__global__ void k_prep(const float* __restrict__ W1s, const float* __restrict__ W2s,
                       const float* __restrict__ b1s, const float* __restrict__ bng,
                       const float* __restrict__ bnb, const float* __restrict__ bnm,
                       const float* __restrict__ bnv,
                       bf16* __restrict__ Wp1, bf16* __restrict__ Wp2,
                       float* __restrict__ sArr, float* __restrict__ tArr) {
    int idx = blockIdx.x * 256 + threadIdx.x;      // [0, 6*16384)
    int l   = idx / 32768;
    int rem = idx - l * 32768;
    int w   = rem >> 14;
    int p   = rem & 16383;
    int j = p & 7, n = (p >> 3) & 127, tq = p >> 10;
    int quad = tq & 3, kk = tq >> 2;
    int k = kk * 32 + quad * 8 + j;
    const float* W = w ? W2s : W1s;
    bf16* Wp = w ? Wp2 : Wp1;
    Wp[l * 16384 + p] = __float2bfloat16(W[l * 16384 + k * 128 + n]);
    if (idx < GDEPTH * 128) {
        int ll = idx >> 7, c = idx & 127;
        float inv = rsqrtf(bnv[ll * 128 + c] + 1e-5f);
        float s = inv * bng[ll * 128 + c];
        sArr[idx] = s;
        tArr[idx] = (b1s[ll * 128 + c] - bnm[ll * 128 + c]) * s + bnb[ll * 128 + c];
    }
}

__global__ void k_convert_x(const float4* __restrict__ x, bf162* __restrict__ h, int n4) {
    int i = blockIdx.x * 256 + threadIdx.x;
    if (i >= n4) return;
    float4 v = x[i];
    bf162 a, b;
    a.x = __float2bfloat16(v.x); a.y = __float2bfloat16(v.y);
    b.x = __float2bfloat16(v.z); b.y = __float2bfloat16(v.w);
    h[2 * i] = a; h[2 * i + 1] = b;
}

// ---------------- sliced CSR build ----------------
#define CSR_CH 4096
__global__ void k_count(const int* __restrict__ ei, int* __restrict__ cnt, int E, int N) {
    int s = blockIdx.x & 7;
    int chunk = blockIdx.x >> 3;
    int lo = (int)((long long)s * N / 8);
    int hi = (int)((long long)(s + 1) * N / 8);
    int base = chunk * CSR_CH;
    #pragma unroll 4
    for (int i = 0; i < CSR_CH / 256; ++i) {
        int e = base + i * 256 + threadIdx.x;
        if (e < E) {
            int d = ei[E + e];
            if (d >= lo && d < hi) atomicAdd(&cnt[d], 1);
        }
    }
}

__global__ void k_scatter(const int* __restrict__ ei, int* __restrict__ fill,
                          int* __restrict__ col, int E, int N) {
    int s = blockIdx.x & 7;
    int chunk = blockIdx.x >> 3;
    int lo = (int)((long long)s * N / 8);
    int hi = (int)((long long)(s + 1) * N / 8);
    int base = chunk * CSR_CH;
    #pragma unroll 4
    for (int i = 0; i < CSR_CH / 256; ++i) {
        int e = base + i * 256 + threadIdx.x;
        if (e < E) {
            int d = ei[E + e];
            if (d >= lo && d < hi) {
                int src = ei[e];
                int pos = atomicAdd(&fill[d], 1);
                col[pos] = src;
            }
        }
    }
}

__global__ void k_scan_blocks(const int* __restrict__ cnt, int* __restrict__ rowp,
                              int* __restrict__ bsums, int n) {
    __shared__ int s[256];
    int t = threadIdx.x;
    int i = blockIdx.x * 256 + t;
    int v = (i < n) ? cnt[i] : 0;
    s[t] = v; __syncthreads();
    for (int o = 1; o < 256; o <<= 1) {
        int u = (t >= o) ? s[t - o] : 0;
        __syncthreads();
        s[t] += u;
        __syncthreads();
    }
    if (i < n) rowp[i] = s[t] - v;
    if (t == 255) bsums[blockIdx.x] = s[255];
}

__global__ void k_scan_sums(int* __restrict__ bsums, int nb) {
    __shared__ int s[512];
    int t = threadIdx.x;
    int v = (t < nb) ? bsums[t] : 0;
    s[t] = v; __syncthreads();
    for (int o = 1; o < 512; o <<= 1) {
        int u = (t >= o) ? s[t - o] : 0;
        __syncthreads();
        s[t] += u;
        __syncthreads();
    }
    if (t < nb) bsums[t] = s[t] - v;
}

__global__ void k_add_off(int* __restrict__ rowp, const int* __restrict__ bsums, int n, int E) {
    int i = blockIdx.x * 256 + threadIdx.x;
    if (i < n) rowp[i] += bsums[blockIdx.x];
    if (i == 0) rowp[n] = E;
}

// ---------------- graph bounds from SORTED batch ----------------
__global__ void k_graph_bounds(const int* __restrict__ batch, int* __restrict__ gp,
                               int n, int G) {
    int i = blockIdx.x * 256 + threadIdx.x;
    if (i >= n) return;
    int b = batch[i];
    if (i == 0) {
        for (int g = 0; g <= b; ++g) gp[g] = 0;
    } else {
        int pb = batch[i - 1];
        if (pb != b) for (int g = pb + 1; g <= b; ++g) gp[g] = i;
    }
    if (i == n - 1) {
        for (int g = b + 1; g <= G; ++g) gp[g] = n;
    }
}

// ---------------- fused layer: z = h + Ah (gather) -> relu(BN(zW1+b1))W2+b2, relu --
__global__ __launch_bounds__(256) void k_layer(const bf16* __restrict__ h,
                                               const int* __restrict__ rowp,
                                               const int* __restrict__ col,
                                               const bf16* __restrict__ Bp1,
                                               const bf16* __restrict__ Bp2,
                                               const float* __restrict__ sv,
                                               const float* __restrict__ tv,
                                               const float* __restrict__ b2,
                                               bf16* __restrict__ Out, int M) {
    __shared__ __align__(16) bf16 As[64 * 136];   // +8 pad
    const int tid = threadIdx.x;
    const int m0 = blockIdx.x * 64;
    const int grp = tid >> 4, c = tid & 15;
    const bf16x8* h8 = (const bf16x8*)h;           // row j chunk c at h8[j*16+c]

    #pragma unroll
    for (int it = 0; it < 4; ++it) {
        int row = grp * 4 + it;
        int node = m0 + row;
        float acc[8];
        if (node < M) {
            bf16x8 self = h8[(size_t)node * 16 + c];
            #pragma unroll
            for (int k = 0; k < 8; ++k) acc[k] = (float)self[k];
            int e = rowp[node], end = rowp[node + 1];
            for (; e + 3 < end; e += 4) {
                int j0 = col[e], j1 = col[e + 1], j2 = col[e + 2], j3 = col[e + 3];
                bf16x8 v0 = h8[(size_t)j0 * 16 + c];
                bf16x8 v1 = h8[(size_t)j1 * 16 + c];
                bf16x8 v2 = h8[(size_t)j2 * 16 + c];
                bf16x8 v3 = h8[(size_t)j3 * 16 + c];
                #pragma unroll
                for (int k = 0; k < 8; ++k)
                    acc[k] += ((float)v0[k] + (float)v1[k]) + ((float)v2[k] + (float)v3[k]);
            }
            for (; e < end; ++e) {
                bf16x8 v = h8[(size_t)col[e] * 16 + c];
                #pragma unroll
                for (int k = 0; k < 8; ++k) acc[k] += (float)v[k];
            }
        } else {
            #pragma unroll
            for (int k = 0; k < 8; ++k) acc[k] = 0.f;
        }
        bf16x8 r;
        #pragma unroll
        for (int k = 0; k < 8; ++k) {
            __hip_bfloat16 t = __float2bfloat16(acc[k]);
            r[k] = *(__bf16*)&t;
        }
        *(bf16x8*)(As + row * 136 + c * 8) = r;
    }
    __syncthreads();

    const int lane = tid & 63;
    const int wid = tid >> 6;
    const int wm = wid & 1, wn = wid >> 1;
    const int l15 = lane & 15, quad = lane >> 4;

    f32x4 acc[2][4];
    #pragma unroll
    for (int i = 0; i < 2; ++i)
        #pragma unroll
        for (int j = 0; j < 4; ++j) acc[i][j] = (f32x4){0.f, 0.f, 0.f, 0.f};
    #pragma unroll
    for (int kk = 0; kk < 4; ++kk) {
        bf16x8 a[2], b[4];
        #pragma unroll
        for (int tn = 0; tn < 4; ++tn)
            b[tn] = *(const bf16x8*)(Bp1 + ((kk * 4 + quad) * 128 + wn * 64 + tn * 16 + l15) * 8);
        #pragma unroll
        for (int tm = 0; tm < 2; ++tm)
            a[tm] = *(const bf16x8*)(As + (wm * 32 + tm * 16 + l15) * 136 + kk * 32 + quad * 8);
        #pragma unroll
        for (int tm = 0; tm < 2; ++tm)
            #pragma unroll
            for (int tn = 0; tn < 4; ++tn)
                acc[tm][tn] = __builtin_amdgcn_mfma_f32_16x16x32_bf16(a[tm], b[tn], acc[tm][tn], 0, 0, 0);
    }
    __syncthreads();                               // all GEMM1 A-reads done
    // epilogue1: y = relu(acc*s + t) -> LDS (C/D: col=lane&15, row=quad*4+reg)
    #pragma unroll
    for (int tn = 0; tn < 4; ++tn) {
        int gc = wn * 64 + tn * 16 + l15;
        float scale = sv[gc], shift = tv[gc];
        #pragma unroll
        for (int tm = 0; tm < 2; ++tm)
            #pragma unroll
            for (int r = 0; r < 4; ++r) {
                float v = fmaxf(acc[tm][tn][r] * scale + shift, 0.f);
                int row = wm * 32 + tm * 16 + quad * 4 + r;
                __hip_bfloat16 t = __float2bfloat16(v);
                As[row * 136 + gc] = *(bf16*)&t;
            }
    }
    __syncthreads();                               // y fully in LDS
    #pragma unroll
    for (int i = 0; i < 2; ++i)
        #pragma unroll
        for (int j = 0; j < 4; ++j) acc[i][j] = (f32x4){0.f, 0.f, 0.f, 0.f};
    #pragma unroll
    for (int kk = 0; kk < 4; ++kk) {
        bf16x8 a[2], b[4];
        #pragma unroll
        for (int tn = 0; tn < 4; ++tn)
            b[tn] = *(const bf16x8*)(Bp2 + ((kk * 4 + quad) * 128 + wn * 64 + tn * 16 + l15) * 8);
        #pragma unroll
        for (int tm = 0; tm < 2; ++tm)
            a[tm] = *(const bf16x8*)(As + (wm * 32 + tm * 16 + l15) * 136 + kk * 32 + quad * 8);
        #pragma unroll
        for (int tm = 0; tm < 2; ++tm)
            #pragma unroll
            for (int tn = 0; tn < 4; ++tn)
                acc[tm][tn] = __builtin_amdgcn_mfma_f32_16x16x32_bf16(a[tm], b[tn], acc[tm][tn], 0, 0, 0);
    }
    // epilogue2: h_next = relu(acc + b2) -> global (different buffer)
    #pragma unroll
    for (int tn = 0; tn < 4; ++tn) {
        int gc = wn * 64 + tn * 16 + l15;
        float shift = b2[gc];
        #pragma unroll
        for (int tm = 0; tm < 2; ++tm)
            #pragma unroll
            for (int r = 0; r < 4; ++r) {
                int gr = m0 + wm * 32 + tm * 16 + quad * 4 + r;
                if (gr < M) {
                    float v = fmaxf(acc[tm][tn][r] + shift, 0.f);
                    Out[(size_t)gr * 128 + gc] = __float2bfloat16(v);
                }
            }
    }
}

// ---------------- pooling: node-chunk parallel, atomic flush at boundaries ------
// Block = 128 threads (feature t), 128 nodes. batch sorted -> ~1-2 flushes/block.
#define PCH 128
__global__ void k_pool(const bf16* __restrict__ h, const int* __restrict__ batch,
                       float* __restrict__ hga, int N) {
    int base = blockIdx.x * PCH;
    if (base >= N) return;
    int t = threadIdx.x;
    int end = base + PCH; if (end > N) end = N;
    int gcur = batch[base];
    float acc = 0.f;
    for (int i = base; i < end; ++i) {
        int g = batch[i];
        if (g != gcur) {
            atomicAdd(&hga[gcur * 128 + t], acc);
            acc = 0.f; gcur = g;
        }
        acc += __bfloat162float(h[(size_t)i * 128 + t]);
    }
    atomicAdd(&hga[gcur * 128 + t], acc);
}

// ---------------- mean + projection + LayerNorm (fp32) ----------------
__global__ void k_proj_ln(const float* __restrict__ hga, const int* __restrict__ gp,
                          const float* __restrict__ Wp,
                          const float* __restrict__ bp, const float* __restrict__ lng,
                          const float* __restrict__ lnb, float* __restrict__ out) {
    __shared__ float row[128];
    __shared__ float red[128];
    int g = blockIdx.x, t = threadIdx.x;
    int cntn = gp[g + 1] - gp[g];
    float inv = 1.0f / (float)(cntn < 1 ? 1 : cntn);
    row[t] = hga[g * 128 + t] * inv;
    __syncthreads();
    float p = bp[t];
    #pragma unroll 8
    for (int k = 0; k < 128; ++k) p += row[k] * Wp[k * 128 + t];
    red[t] = p; __syncthreads();
    for (int o = 64; o > 0; o >>= 1) { if (t < o) red[t] += red[t + o]; __syncthreads(); }
    float mu = red[0] * (1.0f / 128.0f);
    __syncthreads();
    float d = p - mu;
    red[t] = d * d; __syncthreads();
    for (int o = 64; o > 0; o >>= 1) { if (t < o) red[t] += red[t + o]; __syncthreads(); }
    float var = red[0] * (1.0f / 128.0f);
    out[g * 128 + t] = d * rsqrtf(var + 1e-5f) * lng[t] + lnb[t];
}

extern "C" void kernel_launch(void* const* d_in, const int* in_sizes, int n_in,
                              void* d_out, int out_size, void* d_ws, size_t ws_size,
                              hipStream_t stream) {
    const float* x   = (const float*)d_in[0];
    const int*   ei  = (const int*)d_in[1];    // int32: [src(E), dst(E)]
    const int*   bat = (const int*)d_in[2];    // int32, sorted
    const float* W1s = (const float*)d_in[3];
    const float* b1s = (const float*)d_in[4];
    const float* bng = (const float*)d_in[5];
    const float* bnb = (const float*)d_in[6];
    const float* bnm = (const float*)d_in[7];
    const float* bnv = (const float*)d_in[8];
    const float* W2s = (const float*)d_in[9];
    const float* b2s = (const float*)d_in[10];
    const float* Wp  = (const float*)d_in[11];
    const float* bp  = (const float*)d_in[12];
    const float* lng = (const float*)d_in[13];
    const float* lnb = (const float*)d_in[14];
    const int E = in_sizes[1] / 2;
    const int N = in_sizes[2];
    const int G = out_size / 128;

    char* w = (char*)d_ws;
    size_t off = 0;
    auto alloc = [&](size_t b) { char* p = w + off; off += (b + 255) & ~(size_t)255; return p; };
    bf16* buf_a = (bf16*)alloc((size_t)N * 128 * 2);
    bf16* buf_b = (bf16*)alloc((size_t)N * 128 * 2);
    int* col   = (int*)alloc((size_t)E * 4);
    int* cnt   = (int*)alloc((size_t)N * 4);
    int* rowp  = (int*)alloc((size_t)(N + 1) * 4);
    int* fill  = (int*)alloc((size_t)N * 4);
    int* bsums = (int*)alloc(4096);
    int* gp    = (int*)alloc(2048);
    bf16* Wp1  = (bf16*)alloc((size_t)GDEPTH * 16384 * 2);
    bf16* Wp2  = (bf16*)alloc((size_t)GDEPTH * 16384 * 2);
    float* sA  = (float*)alloc((size_t)GDEPTH * 128 * 4);
    float* tA  = (float*)alloc((size_t)GDEPTH * 128 * 4);
    float* hga = (float*)alloc((size_t)G * 128 * 4);

    hipMemsetAsync(cnt, 0, (size_t)N * 4, stream);
    hipMemsetAsync(hga, 0, (size_t)G * 128 * 4, stream);

    k_prep<<<384, 256, 0, stream>>>(W1s, W2s, b1s, bng, bnb, bnm, bnv, Wp1, Wp2, sA, tA);
    k_convert_x<<<(N * 32 + 255) / 256, 256, 0, stream>>>((const float4*)x, (bf162*)buf_a, N * 32);

    int nb = (N + 255) / 256;
    int csr_blocks = ((E + CSR_CH - 1) / CSR_CH) * 8;
    k_count<<<csr_blocks, 256, 0, stream>>>(ei, cnt, E, N);
    k_graph_bounds<<<nb, 256, 0, stream>>>(bat, gp, N, G);
    k_scan_blocks<<<nb, 256, 0, stream>>>(cnt, rowp, bsums, N);
    k_scan_sums<<<1, 512, 0, stream>>>(bsums, nb);
    k_add_off<<<nb, 256, 0, stream>>>(rowp, bsums, N, E);
    hipMemcpyAsync(fill, rowp, (size_t)N * 4, hipMemcpyDeviceToDevice, stream);
    k_scatter<<<csr_blocks, 256, 0, stream>>>(ei, fill, col, E, N);

    const bf16* hcur = buf_a;
    bf16* hnext = buf_b;
    for (int l = 0; l < GDEPTH; ++l) {
        k_layer<<<(N + 63) / 64, 256, 0, stream>>>(hcur, rowp, col,
                                                   Wp1 + (size_t)l * 16384,
                                                   Wp2 + (size_t)l * 16384,
                                                   sA + l * 128, tA + l * 128,
                                                   b2s + l * 128, hnext, N);
        bf16* tmp = hnext; hnext = (bf16*)hcur; hcur = tmp;
    }
    k_pool<<<(N + PCH - 1) / PCH, 128, 0, stream>>>(hcur, bat, hga, N);
    k_proj_ln<<<G, 128, 0, stream>>>(hga, gp, Wp, bp, lng, lnb, (float*)d_out);
}